// Round 14
// baseline (257.897 us; speedup 1.0000x reference)
//
#include <hip/hip_runtime.h>
#include <math.h>

// CapsLayer dynamic routing, MI355X fp32.
// x: [64, 2048, 8]  W: [2048, 32, 8, 16]  out: [64, 32, 16]
// Never materialize u_hat (256 MB); recompute per routing pass.
// R16: BC=16 route1 — double compute per W fragment. Wall model (fits
// R2-R15): per ii a wave waits ~300cy on its 8 W loads then computes ~500cy
// -> ~60% ceiling; every latency-side fix failed. Evidence for the ratio
// lever: route0 (BC0=16, 2x FMA/W-byte) has NEVER appeared in top-5 => it
// beats route1 at identical W-traffic structure. route1 now: sacc[8], each
// wr[8] reused across 8 rows in TWO half-steps of 4 (u[4] transient, per-
// half softmax + barrier => 2 barriers/ii, wsum[2][4][8] buffered by h).
// v: NOT in registers (+32 VGPR = spill-bait per R6/R8); reduce kernels
// materialize v0/vs in global (R3's proven reduce_squash(pre,addsrc) serves
// all 3 reduces, still 6 dispatches); route1 loads 4 v-floats per half per
// ii from L2/L1-hot 128 KB, issued ahead of the u-compute that hides them.
// Spill law (R3/R4/R6/R8): #pragma unroll 1 on ii is load-bearing.
// Tripwires: VGPR <= 128, FETCH <= 100 MB (else spill -> revert to R15),
// absmax 0.00098, route1 <= 48us.

#define B_TOT 64
#define I_TOT 2048
#define D_IN  8
#define NC    32
#define EV    16
#define OD    (NC*EV)      // 512 outputs per b
#define BC    16           // batch rows per block (both route kernels)
#define NBC   (B_TOT/BC)   // 4 b-chunks
#define ICH   8            // i's per block
#define NIC   (I_TOT/ICH)  // 256 i-chunks
#define S_ELEMS (B_TOT*OD) // 32768 floats = 128 KB per v-slice

__device__ __forceinline__ void fma4(float4& acc, float a, const float4& w) {
    acc.x = fmaf(a, w.x, acc.x);
    acc.y = fmaf(a, w.y, acc.y);
    acc.z = fmaf(a, w.z, acc.z);
    acc.w = fmaf(a, w.w, acc.w);
}

// ---- pass 0: c uniform. s0 = sum_i x[b,i,:] @ W[i] — a GEMM, no per-i u.
// BC=16 rows/block: thread (eq,bh,n) folds wr[8] into 8 b-rows directly.
__global__ __launch_bounds__(256, 4)
void route0(const float* __restrict__ x, const float* __restrict__ W,
            float* __restrict__ P)
{
    __shared__ __align__(16) float xl[BC * ICH * D_IN];  // 4 KB

    const int t  = threadIdx.x;
    const int ic = blockIdx.x & (NIC - 1);   // 0..255 (blk%8==ic%8: XCD swz)
    const int bc = blockIdx.x >> 8;          // 0..3
    const int b0 = bc * BC;
    const int i0 = ic * ICH;
    const int eq = t & 3;
    const int bh = (t >> 2) & 1;
    const int n  = t >> 3;

    // stage x[b0..b0+15][i0..i0+7][0..7] (4 KB): 256 float4, one per thread
    {
        const int row = t >> 4, f = (t & 15) * 4;
        *(float4*)&xl[row * (ICH * D_IN) + f] =
            *(const float4*)&x[((size_t)(b0 + row) * I_TOT + i0) * D_IN + f];
    }
    __syncthreads();

    float4 sacc[8];
    #pragma unroll
    for (int q = 0; q < 8; ++q) sacc[q] = make_float4(0.f, 0.f, 0.f, 0.f);

    const float* Wt = &W[(size_t)i0 * 4096 + n * 128 + eq * 4];

    // unroll 1 is load-bearing (spill law); iir de-phases the 4 bc-siblings
    #pragma unroll 1
    for (int ii = 0; ii < ICH; ++ii) {
        const int iir = (ii + bc * 2) & 7;
        float4 wr[8];
        #pragma unroll
        for (int d = 0; d < 8; ++d)
            wr[d] = *(const float4*)&Wt[iir * 4096 + d * 16];

        #pragma unroll
        for (int q = 0; q < 8; ++q) {
            const int bl = bh * 8 + q;
            float4 xa = *(float4*)&xl[bl * (ICH * D_IN) + iir * 8];
            float4 xb = *(float4*)&xl[bl * (ICH * D_IN) + iir * 8 + 4];
            fma4(sacc[q], xa.x, wr[0]); fma4(sacc[q], xa.y, wr[1]);
            fma4(sacc[q], xa.z, wr[2]); fma4(sacc[q], xa.w, wr[3]);
            fma4(sacc[q], xb.x, wr[4]); fma4(sacc[q], xb.y, wr[5]);
            fma4(sacc[q], xb.z, wr[6]); fma4(sacc[q], xb.w, wr[7]);
        }
    }

    #pragma unroll
    for (int q = 0; q < 8; ++q)
        *(float4*)&P[((size_t)ic * B_TOT + b0 + bh * 8 + q) * OD + n * EV + eq * 4] = sacc[q];
}

// ---- passes 1/2: c = softmax_n(u . vin). BC=16: wr[8] reused across 8 rows
// in two half-steps of 4 rows (u[4] transient); v loaded per half from
// global (L2-hot 128 KB), issued before the u-compute that hides it.
// (iter 2 uses vin = v0+v1: dot is linear, so no logit carry needed)
__global__ __launch_bounds__(256, 4)
void route1(const float* __restrict__ x, const float* __restrict__ W,
            float* __restrict__ P, const float* __restrict__ vin)
{
    __shared__ __align__(16) float xl[BC * ICH * D_IN];   // 4 KB
    __shared__ float wsum[2][4][8];                       // buffered by half

    const int t  = threadIdx.x;
    const int ic = blockIdx.x & (NIC - 1);   // 0..255 (blk%8==ic%8: XCD swz)
    const int bc = blockIdx.x >> 8;          // 0..3
    const int b0 = bc * BC;
    const int i0 = ic * ICH;
    const int eq = t & 3;          // e quarter (4 e's)
    const int bh = (t >> 2) & 1;   // row sub-half
    const int n  = t >> 3;         // capsule 0..31
    const int w  = t >> 6;         // wave 0..3

    // stage x[b0..b0+15][i0..i0+7][0..7] (4 KB): 256 float4, one per thread
    {
        const int row = t >> 4, f = (t & 15) * 4;
        *(float4*)&xl[row * (ICH * D_IN) + f] =
            *(const float4*)&x[((size_t)(b0 + row) * I_TOT + i0) * D_IN + f];
    }
    __syncthreads();

    float4 sacc[8];
    #pragma unroll
    for (int q = 0; q < 8; ++q) sacc[q] = make_float4(0.f, 0.f, 0.f, 0.f);

    const float* Wt = &W[(size_t)i0 * 4096 + n * 128 + eq * 4];
    const float* vb = &vin[(size_t)b0 * OD + n * EV + eq * 4];

    // unroll 1 is load-bearing (spill law: R3/R4 hoist -> 1.1 GB scratch).
    #pragma unroll 1
    for (int ii = 0; ii < ICH; ++ii) {
        const int iir = (ii + bc * 2) & 7;
        float4 wr[8];
        #pragma unroll
        for (int d = 0; d < 8; ++d)
            wr[d] = *(const float4*)&Wt[iir * 4096 + d * 16];

        #pragma unroll
        for (int h = 0; h < 2; ++h) {
            // v fragments for this half's 4 rows: issue first, use after the
            // u-compute below (latency hidden under ~256cy of FMA).
            float4 vv[4];
            #pragma unroll
            for (int q = 0; q < 4; ++q)
                vv[q] = *(const float4*)&vb[(size_t)(h * 8 + bh * 4 + q) * OD];

            float4 u[4];
            #pragma unroll
            for (int q = 0; q < 4; ++q) {
                const int bl = h * 8 + bh * 4 + q;
                float4 xa = *(float4*)&xl[bl * (ICH * D_IN) + iir * 8];
                float4 xb = *(float4*)&xl[bl * (ICH * D_IN) + iir * 8 + 4];
                float4 uu = make_float4(0.f, 0.f, 0.f, 0.f);
                fma4(uu, xa.x, wr[0]); fma4(uu, xa.y, wr[1]);
                fma4(uu, xa.z, wr[2]); fma4(uu, xa.w, wr[3]);
                fma4(uu, xb.x, wr[4]); fma4(uu, xb.y, wr[5]);
                fma4(uu, xb.z, wr[6]); fma4(uu, xb.w, wr[7]);
                u[q] = uu;
            }

            float a[4];
            #pragma unroll
            for (int q = 0; q < 4; ++q) {
                float ap = u[q].x * vv[q].x + u[q].y * vv[q].y
                         + u[q].z * vv[q].z + u[q].w * vv[q].w;
                ap += __shfl_xor(ap, 1, 64);
                ap += __shfl_xor(ap, 2, 64);
                a[q] = ap;
            }
            float e[4], p[4];
            #pragma unroll
            for (int q = 0; q < 4; ++q) {
                e[q] = __expf(a[q]);
                float pp = e[q];
                pp += __shfl_xor(pp, 8, 64);
                pp += __shfl_xor(pp, 16, 64);
                pp += __shfl_xor(pp, 32, 64);
                p[q] = pp;       // sum over n in this wave, rows of half h
            }
            if (eq == 0) {
                #pragma unroll
                for (int q = 0; q < 4; ++q)
                    wsum[h][w][bh * 4 + q] = p[q];
            }
            __syncthreads();   // protects wsum[h]; next write to wsum[h] is
                               // after the h-of-next-step barrier (safe WAR)
            #pragma unroll
            for (int q = 0; q < 4; ++q) {
                const int rl = bh * 4 + q;
                float s = wsum[h][0][rl] + wsum[h][1][rl]
                        + wsum[h][2][rl] + wsum[h][3][rl];
                float c = __fdividef(e[q], s);
                fma4(sacc[h * 4 + q], c, u[q]);
            }
        }
    }

    #pragma unroll
    for (int h = 0; h < 2; ++h)
        #pragma unroll
        for (int q = 0; q < 4; ++q)
            *(float4*)&P[((size_t)ic * B_TOT + b0 + h * 8 + bh * 4 + q) * OD
                         + n * EV + eq * 4] = sacc[h * 4 + q];
}

// ---- reduce P over 256 i-chunks, squash, write v (or out). 512 blocks
// (b x 8 o-slices), exclusive writes. If addsrc != null, dst += addsrc
// (produces vs = v0 + v1 for pass 2 via dot linearity).
__global__ __launch_bounds__(256, 4)
void reduce_sq(const float* __restrict__ P, float* __restrict__ dst,
               const float* __restrict__ addsrc, float pre)
{
    __shared__ float red[256];
    const int b   = blockIdx.x >> 3;
    const int oq  = blockIdx.x & 7;
    const int t   = threadIdx.x;
    const int o   = oq * 64 + (t & 63);
    const int icq = t >> 6;                       // 0..3
    const size_t stride = (size_t)B_TOT * OD;

    float acc = 0.f;
    size_t base = ((size_t)(icq * 64) * B_TOT + b) * OD + o;
    #pragma unroll 8
    for (int k = 0; k < 64; ++k) acc += P[base + (size_t)k * stride];
    red[t] = acc;
    __syncthreads();

    if (t < 64) {
        float v = (red[t] + red[t + 64] + red[t + 128] + red[t + 192]) * pre;
        float q2 = v * v;
        q2 += __shfl_xor(q2, 1, 64);
        q2 += __shfl_xor(q2, 2, 64);
        q2 += __shfl_xor(q2, 4, 64);
        q2 += __shfl_xor(q2, 8, 64);
        float sc = q2 / ((1.0f + q2) * sqrtf(q2));
        float outv = v * sc;
        if (addsrc) outv += addsrc[(size_t)b * OD + o];
        dst[(size_t)b * OD + o] = outv;
    }
}

extern "C" void kernel_launch(void* const* d_in, const int* in_sizes, int n_in,
                              void* d_out, int out_size, void* d_ws, size_t ws_size,
                              hipStream_t stream) {
    const float* x = (const float*)d_in[0];
    const float* W = (const float*)d_in[1];
    float* out = (float*)d_out;

    char* ws = (char*)d_ws;
    float* P  = (float*)ws;                               // 32 MB
    float* v0 = (float*)(ws + (size_t)32 * 1024 * 1024);  // 128 KB each
    float* vs = v0 + S_ELEMS;                             // v0 + v1

    dim3 rg(NBC * NIC), rb(256);   // 1024 blocks (both route kernels)
    dim3 sg(B_TOT * 8), sb(256);   // 512 blocks

    // iter 0: uniform c (1/32 applied as pre in the v0 squash)
    route0<<<rg, rb, 0, stream>>>(x, W, P);
    reduce_sq<<<sg, sb, 0, stream>>>(P, v0, nullptr, 1.0f / 32.0f);
    // iter 1: c = softmax(u . v0)
    route1<<<rg, rb, 0, stream>>>(x, W, P, v0);
    // vs = v0 + v1  (iter-2 logits: u.v0 + u.v1 = u.(v0+v1))
    reduce_sq<<<sg, sb, 0, stream>>>(P, vs, v0, 1.0f);
    // iter 2: c = softmax(u . vs); final
    route1<<<rg, rb, 0, stream>>>(x, W, P, vs);
    reduce_sq<<<sg, sb, 0, stream>>>(P, out, nullptr, 1.0f);
}

// Round 15
// 191.361 us; speedup vs baseline: 1.3477x; 1.3477x over previous
//
#include <hip/hip_runtime.h>
#include <math.h>

// CapsLayer dynamic routing, MI355X fp32.
// x: [64, 2048, 8]  W: [2048, 32, 8, 16]  out: [64, 32, 16]
// Never materialize u_hat (256 MB); recompute per routing pass.
// R17: recombination of proven-best pieces, no new structure.
//   - route1 = R13's vin-reading BC=8 body (42.9us, fastest measured) +
//     R15's sibling de-phase. NOT R14's inline squash (+4us/pass measured).
//   - reduce_sq = R16's fused reduce+squash(+addsrc) -> materializes v0/vs
//     in one kernel; 6 dispatches total.
//   - route0 = R16's BC=16 GEMM form (2x FMA per W byte, never in top-5).
// Spill law (R3/R4/R6/R8/R16, 4 confirmations): route bodies cannot hold
// >~60 live VGPRs; BC=16-with-softmax and register W-pipelines all spill.
// #pragma unroll 1 on the ii loop is load-bearing everywhere.
// Tripwires: route1 <= 47us, FETCH <= 80 MB (spill), VGPR <= 64,
// absmax 0.00098.

#define B_TOT 64
#define I_TOT 2048
#define D_IN  8
#define NC    32
#define EV    16
#define OD    (NC*EV)      // 512 outputs per b
#define BC    8            // batch rows per block (softmax passes)
#define NBC   (B_TOT/BC)   // 8 b-chunks
#define BC0   16           // batch rows per block (pass-0 GEMM)
#define NBC0  (B_TOT/BC0)  // 4 b-chunks
#define ICH   8            // i's per block
#define NIC   (I_TOT/ICH)  // 256 i-chunks
#define S_ELEMS (B_TOT*OD) // 32768 floats = 128 KB per v-slice

__device__ __forceinline__ void fma4(float4& acc, float a, const float4& w) {
    acc.x = fmaf(a, w.x, acc.x);
    acc.y = fmaf(a, w.y, acc.y);
    acc.z = fmaf(a, w.z, acc.z);
    acc.w = fmaf(a, w.w, acc.w);
}

// ---- pass 0: c uniform. s0 = sum_i x[b,i,:] @ W[i] — a GEMM, no per-i u.
// BC0=16 rows/block: thread (eq,bh,n) folds wr[8] into 8 b-rows directly.
__global__ __launch_bounds__(256, 4)
void route0(const float* __restrict__ x, const float* __restrict__ W,
            float* __restrict__ P)
{
    __shared__ __align__(16) float xl[BC0 * ICH * D_IN];  // 4 KB

    const int t  = threadIdx.x;
    const int ic = blockIdx.x & (NIC - 1);   // 0..255 (blk%8==ic%8: XCD swz)
    const int bc = blockIdx.x >> 8;          // 0..3
    const int b0 = bc * BC0;
    const int i0 = ic * ICH;
    const int eq = t & 3;
    const int bh = (t >> 2) & 1;
    const int n  = t >> 3;

    // stage x[b0..b0+15][i0..i0+7][0..7] (4 KB): 256 float4, one per thread
    {
        const int row = t >> 4, f = (t & 15) * 4;
        *(float4*)&xl[row * (ICH * D_IN) + f] =
            *(const float4*)&x[((size_t)(b0 + row) * I_TOT + i0) * D_IN + f];
    }
    __syncthreads();

    float4 sacc[8];
    #pragma unroll
    for (int q = 0; q < 8; ++q) sacc[q] = make_float4(0.f, 0.f, 0.f, 0.f);

    const float* Wt = &W[(size_t)i0 * 4096 + n * 128 + eq * 4];

    // unroll 1 is load-bearing (spill law); iir de-phases the 4 bc-siblings
    #pragma unroll 1
    for (int ii = 0; ii < ICH; ++ii) {
        const int iir = (ii + bc * 2) & 7;
        float4 wr[8];
        #pragma unroll
        for (int d = 0; d < 8; ++d)
            wr[d] = *(const float4*)&Wt[iir * 4096 + d * 16];

        #pragma unroll
        for (int q = 0; q < 8; ++q) {
            const int bl = bh * 8 + q;
            float4 xa = *(float4*)&xl[bl * (ICH * D_IN) + iir * 8];
            float4 xb = *(float4*)&xl[bl * (ICH * D_IN) + iir * 8 + 4];
            fma4(sacc[q], xa.x, wr[0]); fma4(sacc[q], xa.y, wr[1]);
            fma4(sacc[q], xa.z, wr[2]); fma4(sacc[q], xa.w, wr[3]);
            fma4(sacc[q], xb.x, wr[4]); fma4(sacc[q], xb.y, wr[5]);
            fma4(sacc[q], xb.z, wr[6]); fma4(sacc[q], xb.w, wr[7]);
        }
    }

    #pragma unroll
    for (int q = 0; q < 8; ++q)
        *(float4*)&P[((size_t)ic * B_TOT + b0 + bh * 8 + q) * OD + n * EV + eq * 4] = sacc[q];
}

// ---- passes 1/2: c = softmax_n(u . vin). R13's proven 42.9us body (vin
// materialized by reduce_sq, read once into vr[4]) + R15 sibling de-phase.
// (iter 2 uses vin = v0+v1: dot is linear, so no logit carry needed)
__global__ __launch_bounds__(256, 4)
void route1(const float* __restrict__ x, const float* __restrict__ W,
            float* __restrict__ P, const float* __restrict__ vin)
{
    __shared__ __align__(16) float xl[BC * ICH * D_IN];   // 2 KB
    __shared__ float wsum[2][4][BC];                      // 256 B (ii-dbuf)

    const int t  = threadIdx.x;
    const int ic = blockIdx.x & (NIC - 1);   // 0..255 (blk%8==ic%8: XCD swz)
    const int bc = blockIdx.x >> 8;          // 0..7
    const int b0 = bc * BC;
    const int i0 = ic * ICH;
    const int eq = t & 3;          // e quarter (4 e's)
    const int bh = (t >> 2) & 1;   // b half (4 b's each)
    const int n  = t >> 3;         // capsule 0..31
    const int w  = t >> 6;         // wave 0..3

    if (t < 128) {
        const int row = t >> 4, f = (t & 15) * 4;
        *(float4*)&xl[row * (ICH * D_IN) + f] =
            *(const float4*)&x[((size_t)(b0 + row) * I_TOT + i0) * D_IN + f];
    }

    float4 vr[4];
    #pragma unroll
    for (int q = 0; q < 4; ++q)
        vr[q] = *(const float4*)&vin[(size_t)(b0 + bh * 4 + q) * OD + n * EV + eq * 4];
    __syncthreads();

    float4 sacc[4];
    #pragma unroll
    for (int q = 0; q < 4; ++q) sacc[q] = make_float4(0.f, 0.f, 0.f, 0.f);

    const float* Wt = &W[(size_t)i0 * 4096 + n * 128 + eq * 4];

    // unroll 1 is load-bearing (spill law: R3/R4 hoist -> 1.1 GB scratch).
    // iir = (ii + bc) & 7 de-phases the 8 bc-siblings of this ic.
    #pragma unroll 1
    for (int ii = 0; ii < ICH; ++ii) {
        const int iir = (ii + bc) & 7;
        float4 wr[8];
        #pragma unroll
        for (int d = 0; d < 8; ++d)
            wr[d] = *(const float4*)&Wt[iir * 4096 + d * 16];

        float4 u[4];
        #pragma unroll
        for (int q = 0; q < 4; ++q) {
            const int bl = bh * 4 + q;
            float4 xa = *(float4*)&xl[bl * (ICH * D_IN) + iir * 8];
            float4 xb = *(float4*)&xl[bl * (ICH * D_IN) + iir * 8 + 4];
            float4 uu = make_float4(0.f, 0.f, 0.f, 0.f);
            fma4(uu, xa.x, wr[0]); fma4(uu, xa.y, wr[1]);
            fma4(uu, xa.z, wr[2]); fma4(uu, xa.w, wr[3]);
            fma4(uu, xb.x, wr[4]); fma4(uu, xb.y, wr[5]);
            fma4(uu, xb.z, wr[6]); fma4(uu, xb.w, wr[7]);
            u[q] = uu;
        }

        float a[4];
        #pragma unroll
        for (int q = 0; q < 4; ++q) {
            float ap = u[q].x * vr[q].x + u[q].y * vr[q].y
                     + u[q].z * vr[q].z + u[q].w * vr[q].w;
            ap += __shfl_xor(ap, 1, 64);
            ap += __shfl_xor(ap, 2, 64);
            a[q] = ap;
        }
        float e[4], p[4];
        #pragma unroll
        for (int q = 0; q < 4; ++q) {
            e[q] = __expf(a[q]);
            float pp = e[q];
            pp += __shfl_xor(pp, 8, 64);
            pp += __shfl_xor(pp, 16, 64);
            pp += __shfl_xor(pp, 32, 64);
            p[q] = pp;
        }
        if (eq == 0) {
            #pragma unroll
            for (int q = 0; q < 4; ++q)
                wsum[ii & 1][w][bh * 4 + q] = p[q];
        }
        __syncthreads();
        #pragma unroll
        for (int q = 0; q < 4; ++q) {
            const int bl = bh * 4 + q;
            float s = wsum[ii & 1][0][bl] + wsum[ii & 1][1][bl]
                    + wsum[ii & 1][2][bl] + wsum[ii & 1][3][bl];
            float c = e[q] / s;
            fma4(sacc[q], c, u[q]);
        }
    }

    #pragma unroll
    for (int q = 0; q < 4; ++q)
        *(float4*)&P[((size_t)ic * B_TOT + b0 + bh * 4 + q) * OD + n * EV + eq * 4] = sacc[q];
}

// ---- reduce P over 256 i-chunks, squash, write v (or out). 512 blocks
// (b x 8 o-slices), exclusive writes. If addsrc != null, dst += addsrc
// (produces vs = v0 + v1 for pass 2 via dot linearity).
__global__ __launch_bounds__(256, 4)
void reduce_sq(const float* __restrict__ P, float* __restrict__ dst,
               const float* __restrict__ addsrc, float pre)
{
    __shared__ float red[256];
    const int b   = blockIdx.x >> 3;
    const int oq  = blockIdx.x & 7;
    const int t   = threadIdx.x;
    const int o   = oq * 64 + (t & 63);
    const int icq = t >> 6;                       // 0..3
    const size_t stride = (size_t)B_TOT * OD;

    float acc = 0.f;
    size_t base = ((size_t)(icq * 64) * B_TOT + b) * OD + o;
    #pragma unroll 8
    for (int k = 0; k < 64; ++k) acc += P[base + (size_t)k * stride];
    red[t] = acc;
    __syncthreads();

    if (t < 64) {
        float v = (red[t] + red[t + 64] + red[t + 128] + red[t + 192]) * pre;
        float q2 = v * v;
        q2 += __shfl_xor(q2, 1, 64);
        q2 += __shfl_xor(q2, 2, 64);
        q2 += __shfl_xor(q2, 4, 64);
        q2 += __shfl_xor(q2, 8, 64);
        float sc = q2 / ((1.0f + q2) * sqrtf(q2));
        float outv = v * sc;
        if (addsrc) outv += addsrc[(size_t)b * OD + o];
        dst[(size_t)b * OD + o] = outv;
    }
}

extern "C" void kernel_launch(void* const* d_in, const int* in_sizes, int n_in,
                              void* d_out, int out_size, void* d_ws, size_t ws_size,
                              hipStream_t stream) {
    const float* x = (const float*)d_in[0];
    const float* W = (const float*)d_in[1];
    float* out = (float*)d_out;

    char* ws = (char*)d_ws;
    float* P  = (float*)ws;                               // 32 MB
    float* v0 = (float*)(ws + (size_t)32 * 1024 * 1024);  // 128 KB each
    float* vs = v0 + S_ELEMS;                             // v0 + v1

    dim3 r0g(NBC0 * NIC), r1g(NBC * NIC), rb(256);  // 1024 / 2048 blocks
    dim3 sg(B_TOT * 8), sb(256);                    // 512 blocks

    // iter 0: uniform c (1/32 applied as pre in the v0 squash)
    route0<<<r0g, rb, 0, stream>>>(x, W, P);
    reduce_sq<<<sg, sb, 0, stream>>>(P, v0, nullptr, 1.0f / 32.0f);
    // iter 1: c = softmax(u . v0)
    route1<<<r1g, rb, 0, stream>>>(x, W, P, v0);
    // vs = v0 + v1  (iter-2 logits: u.v0 + u.v1 = u.(v0+v1))
    reduce_sq<<<sg, sb, 0, stream>>>(P, vs, v0, 1.0f);
    // iter 2: c = softmax(u . vs); final
    route1<<<r1g, rb, 0, stream>>>(x, W, P, vs);
    reduce_sq<<<sg, sb, 0, stream>>>(P, out, nullptr, 1.0f);
}